// Round 5
// baseline (233.474 us; speedup 1.0000x reference)
//
#include <hip/hip_runtime.h>
#include <math.h>

#define NROWS 8192
#define DIM   1024
#define BT    256              // tile edge
#define NCHUNK 32              // 8192 / 256 column chunks
#define NTRI  528              // 32*33/2 lower-triangle tiles
#define GRID  512
#define NKT   32               // 1024 / BK
#define BK    32               // K elements per step (64 B per row)

typedef __bf16 bf16x8 __attribute__((ext_vector_type(8)));
typedef float  f32x4  __attribute__((ext_vector_type(4)));

// fp32 -> bf16 (RNE)
__device__ __forceinline__ unsigned short f2bf(float f) {
    unsigned int u = __float_as_uint(f);
    u = (u + 0x7FFFu + ((u >> 16) & 1u)) >> 16;
    return (unsigned short)u;
}

__device__ __forceinline__ void gld16(const void* g, void* l) {
    __builtin_amdgcn_global_load_lds(
        (__attribute__((address_space(1))) void*)g,
        (__attribute__((address_space(3))) void*)l,
        16, 0, 0);
}

template<int N>
__device__ __forceinline__ float dppror(float v) {
    return __int_as_float(__builtin_amdgcn_update_dpp(
        0, __float_as_int(v), 0x120 + N, 0xF, 0xF, false));
}

__device__ __forceinline__ void t2push(float& a1, float& a2, float v) {
    float hi = fmaxf(a1, v);
    float lo = fminf(a1, v);
    a1 = hi;
    a2 = fmaxf(a2, lo);
}

__device__ __forceinline__ void t2merge(float& a1, float& a2, float b1, float b2) {
    float hi = fmaxf(a1, b1);
    float lo = fminf(a1, b1);
    a1 = hi;
    a2 = fmaxf(fmaxf(a2, b2), lo);
}

// ---------------- Kernel A: row L2-normalize, fp32 -> bf16 ----------------
__global__ __launch_bounds__(256) void knorm(const float* __restrict__ x,
                                             unsigned short* __restrict__ xn) {
    const int w = threadIdx.x >> 6, lane = threadIdx.x & 63;
    const int row = blockIdx.x * 4 + w;
    const float4* src = (const float4*)(x + (size_t)row * DIM);
    float4 v[4];
    float ss = 0.0f;
    #pragma unroll
    for (int i = 0; i < 4; i++) {
        v[i] = src[lane + 64 * i];
        ss += v[i].x * v[i].x + v[i].y * v[i].y + v[i].z * v[i].z + v[i].w * v[i].w;
    }
    #pragma unroll
    for (int d = 1; d < 64; d <<= 1) ss += __shfl_xor(ss, d);
    const float inv = 1.0f / fmaxf(sqrtf(ss), 1e-8f);
    unsigned short* dst = xn + (size_t)row * DIM;
    #pragma unroll
    for (int i = 0; i < 4; i++) {
        uint2 o;
        o.x = (unsigned)f2bf(v[i].x * inv) | ((unsigned)f2bf(v[i].y * inv) << 16);
        o.y = (unsigned)f2bf(v[i].z * inv) | ((unsigned)f2bf(v[i].w * inv) << 16);
        *(uint2*)(dst + (size_t)(lane + 64 * i) * 4) = o;
    }
}

// ------- Kernel B: symmetric 256x256 gram, 8 waves, BK=32,
// 4-buffer LDS + cross-iteration REGISTER double-buffer, counted vmcnt/lgkmcnt.
__global__ __launch_bounds__(512, 2) void kgram(const unsigned short* __restrict__ xn,
                                                float2* __restrict__ top2) {
    __shared__ __align__(16) char smem[143360];  // 4x32KB bufs + 12KB reduce scratch
    float (*st2r)[256][2] = (float (*)[256][2])(smem + 131072);         // [4][256][2]
    float (*st2c)[256][2] = (float (*)[256][2])(smem + 131072 + 8192);  // [2][256][2]

    const int t = threadIdx.x;
    const int lane = t & 63;
    const int w = t >> 6;            // 0..7
    const int wr = w >> 2, wc = w & 3;
    const int g = lane >> 4, c = lane & 15;

    // fragment LDS byte offset; swizzle: chunk g of row r stored at slot g ^ ((r>>1)&3)
    const int LA = c * 64 + (((g ^ ((c >> 1) & 3)) & 3) << 4);

    // staging: thread covers LDS chunk-slots q0=t, q1=512+t of each panel
    const int q0 = t, q1 = 512 + t;
    const int r0 = q0 >> 2, g0 = (q0 & 3) ^ ((r0 >> 1) & 3);
    const int r1 = q1 >> 2, g1 = (q1 & 3) ^ ((r1 >> 1) & 3);

    const int bswz = (blockIdx.x & 7) * (GRID / 8) + (blockIdx.x >> 3);

    for (int tix = bswz; tix < NTRI; tix += GRID) {
        int by = (int)((sqrtf(8.0f * (float)tix + 1.0f) - 1.0f) * 0.5f);
        while ((by + 1) * (by + 2) / 2 <= tix) by++;
        while (by * (by + 1) / 2 > tix) by--;
        const int bx = tix - by * (by + 1) / 2;
        const bool diagTile = (bx == by);

        const unsigned short* sA0 = xn + (size_t)(by * BT + r0) * DIM + g0 * 8;
        const unsigned short* sA1 = xn + (size_t)(by * BT + r1) * DIM + g1 * 8;
        const unsigned short* sB0 = xn + (size_t)(bx * BT + r0) * DIM + g0 * 8;
        const unsigned short* sB1 = xn + (size_t)(bx * BT + r1) * DIM + g1 * 8;

        f32x4 acc[8][4];
        #pragma unroll
        for (int m = 0; m < 8; m++)
            #pragma unroll
            for (int n = 0; n < 4; n++) acc[m][n] = (f32x4)0.0f;

        bf16x8 afA[8], bfA[4], afB[8], bfB[4];

#define STAGE(BUF, KT) do {                                  \
        char* _b = smem + (BUF) * 32768;                     \
        gld16(sA0 + (KT) * BK, _b + q0 * 16);                \
        gld16(sA1 + (KT) * BK, _b + q1 * 16);                \
        gld16(sB0 + (KT) * BK, _b + 16384 + q0 * 16);        \
        gld16(sB1 + (KT) * BK, _b + 16384 + q1 * 16);        \
    } while (0)

#define LDFRAG(AF, BF, BUF) do {                                          \
        const char* _ab = smem + (BUF) * 32768 + wr * 8192 + LA;          \
        const char* _bb = smem + (BUF) * 32768 + 16384 + wc * 4096 + LA;  \
        AF[0] = *(const bf16x8*)(_ab + 0 * 1024);                         \
        AF[1] = *(const bf16x8*)(_ab + 1 * 1024);                         \
        AF[2] = *(const bf16x8*)(_ab + 2 * 1024);                         \
        AF[3] = *(const bf16x8*)(_ab + 3 * 1024);                         \
        AF[4] = *(const bf16x8*)(_ab + 4 * 1024);                         \
        AF[5] = *(const bf16x8*)(_ab + 5 * 1024);                         \
        AF[6] = *(const bf16x8*)(_ab + 6 * 1024);                         \
        AF[7] = *(const bf16x8*)(_ab + 7 * 1024);                         \
        BF[0] = *(const bf16x8*)(_bb + 0 * 1024);                         \
        BF[1] = *(const bf16x8*)(_bb + 1 * 1024);                         \
        BF[2] = *(const bf16x8*)(_bb + 2 * 1024);                         \
        BF[3] = *(const bf16x8*)(_bb + 3 * 1024);                         \
    } while (0)

#define MFMA32(AF, BF) do {                                               \
        _Pragma("unroll")                                                 \
        for (int _m = 0; _m < 8; _m++)                                    \
            _Pragma("unroll")                                             \
            for (int _n = 0; _n < 4; _n++)                                \
                acc[_m][_n] = __builtin_amdgcn_mfma_f32_16x16x32_bf16(    \
                    AF[_m], BF[_n], acc[_m][_n], 0, 0, 0);                \
    } while (0)

#define KBODY(KT_STAGE, DO_STAGE, VM, LGK, CURA, CURB, NXTA, NXTB, NBUF)  \
    do {                                                                  \
        asm volatile("s_waitcnt vmcnt(" #VM ")" ::: "memory");            \
        __builtin_amdgcn_s_barrier();                                     \
        __builtin_amdgcn_sched_barrier(0);                                \
        LDFRAG(NXTA, NXTB, (NBUF));                                       \
        if (DO_STAGE) STAGE(((NBUF) + 2) & 3, (KT_STAGE));                \
        asm volatile("s_waitcnt lgkmcnt(" #LGK ")" ::: "memory");         \
        __builtin_amdgcn_sched_barrier(0);                                \
        __builtin_amdgcn_s_setprio(1);                                    \
        MFMA32(CURA, CURB);                                               \
        __builtin_amdgcn_s_setprio(0);                                    \
        __builtin_amdgcn_sched_barrier(0);                                \
    } while (0)

        // prologue: stage tiles 0..2, wait tile 0, load its fragments
        STAGE(0, 0);
        STAGE(1, 1);
        STAGE(2, 2);
        asm volatile("s_waitcnt vmcnt(8)" ::: "memory");
        __builtin_amdgcn_s_barrier();
        __builtin_amdgcn_sched_barrier(0);
        LDFRAG(afA, bfA, 0);

        // main loop: j = 4*jj + b, b=0..3, j = 0..27
        for (int jj = 0; jj < 7; ++jj) {
            const int j0 = 4 * jj;
            KBODY(j0 + 3, 1, 4, 12, afA, bfA, afB, bfB, 1);
            KBODY(j0 + 4, 1, 4, 12, afB, bfB, afA, bfA, 2);
            KBODY(j0 + 5, 1, 4, 12, afA, bfA, afB, bfB, 3);
            KBODY(j0 + 6, 1, 4, 12, afB, bfB, afA, bfA, 0);
        }
        // tail: j = 28 (stages S31), 29, 30 (full drain), 31
        KBODY(31, 1, 4, 12, afA, bfA, afB, bfB, 1);
        KBODY(0,  0, 4, 12, afB, bfB, afA, bfA, 2);
        KBODY(0,  0, 0, 12, afA, bfA, afB, bfB, 3);
        asm volatile("s_waitcnt lgkmcnt(0)" ::: "memory");
        __builtin_amdgcn_sched_barrier(0);
        __builtin_amdgcn_s_setprio(1);
        MFMA32(afB, bfB);
        __builtin_amdgcn_s_setprio(0);
        __builtin_amdgcn_sched_barrier(0);

#undef KBODY
#undef MFMA32
#undef LDFRAG
#undef STAGE

        // ---- per-row top-2 (rows of by-block) ----
        #pragma unroll
        for (int m = 0; m < 8; m++) {
            #pragma unroll
            for (int rr = 0; rr < 4; rr++) {
                const int lrow = wr * 128 + m * 16 + g * 4 + rr;
                float a1 = -1e30f, a2 = -1e30f;
                #pragma unroll
                for (int n = 0; n < 4; n++) {
                    float v = acc[m][n][rr];
                    if (diagTile && (wc * 64 + n * 16 + c) == lrow) v = -2.0f;
                    t2push(a1, a2, v);
                }
                { float b1 = dppror<1>(a1), b2 = dppror<1>(a2); t2merge(a1, a2, b1, b2); }
                { float b1 = dppror<2>(a1), b2 = dppror<2>(a2); t2merge(a1, a2, b1, b2); }
                { float b1 = dppror<4>(a1), b2 = dppror<4>(a2); t2merge(a1, a2, b1, b2); }
                { float b1 = dppror<8>(a1), b2 = dppror<8>(a2); t2merge(a1, a2, b1, b2); }
                if (c == 0) { st2r[wc][lrow][0] = a1; st2r[wc][lrow][1] = a2; }
            }
        }
        // ---- per-col top-2 (rows of bx-block via symmetry) ----
        if (!diagTile) {
            #pragma unroll
            for (int n = 0; n < 4; n++) {
                const int lcol = wc * 64 + n * 16 + c;
                float a1 = -1e30f, a2 = -1e30f;
                #pragma unroll
                for (int m = 0; m < 8; m++)
                    #pragma unroll
                    for (int rr = 0; rr < 4; rr++)
                        t2push(a1, a2, acc[m][n][rr]);
                #pragma unroll
                for (int d = 16; d < 64; d <<= 1) {
                    float b1 = __shfl_xor(a1, d);
                    float b2 = __shfl_xor(a2, d);
                    t2merge(a1, a2, b1, b2);
                }
                if (g == 0) { st2c[wr][lcol][0] = a1; st2c[wr][lcol][1] = a2; }
            }
        }
        __syncthreads();
        if (t < 256) {
            float a1 = st2r[0][t][0], a2 = st2r[0][t][1];
            t2merge(a1, a2, st2r[1][t][0], st2r[1][t][1]);
            t2merge(a1, a2, st2r[2][t][0], st2r[2][t][1]);
            t2merge(a1, a2, st2r[3][t][0], st2r[3][t][1]);
            top2[(size_t)(by * BT + t) * NCHUNK + bx] = make_float2(a1, a2);
        } else if (!diagTile) {
            const int tc = t - 256;
            float a1 = st2c[0][tc][0], a2 = st2c[0][tc][1];
            t2merge(a1, a2, st2c[1][tc][0], st2c[1][tc][1]);
            top2[(size_t)(bx * BT + tc) * NCHUNK + by] = make_float2(a1, a2);
        }
        __syncthreads();
    }
}

// ------- Kernel C: one wave per row; lanes 0..31 <-> chunks; loss/gate -------
__global__ __launch_bounds__(256) void kloss(const float2* __restrict__ top2,
                                             float2* __restrict__ partials) {
    const int t = threadIdx.x;
    const int w = t >> 6, lane = t & 63;
    const int row = blockIdx.x * 4 + w;   // 2048 blocks x 4 waves
    float a1 = -1e30f, a2 = -1e30f;
    if (lane < NCHUNK) {
        float2 q = top2[(size_t)row * NCHUNK + lane];
        a1 = q.x; a2 = q.y;
    }
    #pragma unroll
    for (int d = 1; d < 64; d <<= 1) {
        float b1 = __shfl_xor(a1, d);
        float b2 = __shfl_xor(a2, d);
        t2merge(a1, a2, b1, b2);
    }
    __shared__ float2 wsum[4];
    if (lane == 0) {
        float slg = 0.0f, sg = 0.0f;
        float vs[2] = {a1, a2};
        #pragma unroll
        for (int i = 0; i < 2; i++) {
            float dd = sqrtf(fmaxf(2.0f - 2.0f * vs[i], 0.0f));
            float loss = -logf(dd + 1e-8f);
            float gate = 1.0f / (1.0f + expf(-(loss - 0.5f) * 10.0f));
            slg += loss * gate;
            sg += gate;
        }
        wsum[w] = make_float2(slg, sg);
    }
    __syncthreads();
    if (t == 0) {
        float a = 0.0f, b = 0.0f;
        #pragma unroll
        for (int i = 0; i < 4; i++) { a += wsum[i].x; b += wsum[i].y; }
        partials[blockIdx.x] = make_float2(a, b);
    }
}

// ---------------- Kernel D: final scalar over 2048 partials ----------------
__global__ __launch_bounds__(256) void kfinal(const float2* __restrict__ partials,
                                              float* __restrict__ out) {
    const int t = threadIdx.x;
    float a = 0.0f, b = 0.0f;
    for (int i = t; i < 2048; i += 256) {
        float2 p = partials[i];
        a += p.x; b += p.y;
    }
    #pragma unroll
    for (int d = 1; d < 64; d <<= 1) {
        a += __shfl_xor(a, d);
        b += __shfl_xor(b, d);
    }
    __shared__ float2 ws4[4];
    if ((t & 63) == 0) ws4[t >> 6] = make_float2(a, b);
    __syncthreads();
    if (t == 0) {
        float A = 0.0f, Bb = 0.0f;
        #pragma unroll
        for (int i = 0; i < 4; i++) { A += ws4[i].x; Bb += ws4[i].y; }
        float wm = A / 16384.0f;
        float gm = A / fmaxf(Bb, 1.0f);
        out[0] = 0.5f * wm + 0.5f * gm;
    }
}

extern "C" void kernel_launch(void* const* d_in, const int* in_sizes, int n_in,
                              void* d_out, int out_size, void* d_ws, size_t ws_size,
                              hipStream_t stream) {
    const float* x = (const float*)d_in[0];
    unsigned short* xn = (unsigned short*)d_ws;                              // 16 MB
    float2* top2 = (float2*)((char*)d_ws + (size_t)16 * 1024 * 1024);        // 2 MB
    float2* partials = (float2*)((char*)d_ws + (size_t)20 * 1024 * 1024);    // 16 KB
    float* out = (float*)d_out;

    knorm<<<NROWS / 4, 256, 0, stream>>>(x, xn);
    kgram<<<GRID, 512, 0, stream>>>(xn, top2);
    kloss<<<2048, 256, 0, stream>>>(top2, partials);
    kfinal<<<1, 256, 0, stream>>>(partials, out);
}

// Round 6
// 180.650 us; speedup vs baseline: 1.2924x; 1.2924x over previous
//
#include <hip/hip_runtime.h>
#include <math.h>

#define NROWS 8192
#define DIM   1024
#define BT    256              // tile edge
#define NCHUNK 32              // 8192 / 256 column chunks
#define NTRI  528              // 32*33/2 lower-triangle tiles
#define NKT   16               // 1024 / BK
#define BK    64

typedef __bf16 bf16x8 __attribute__((ext_vector_type(8)));
typedef float  f32x4  __attribute__((ext_vector_type(4)));

// fp32 -> bf16 (RNE)
__device__ __forceinline__ unsigned short f2bf(float f) {
    unsigned int u = __float_as_uint(f);
    u = (u + 0x7FFFu + ((u >> 16) & 1u)) >> 16;
    return (unsigned short)u;
}

__device__ __forceinline__ void gld16(const void* g, void* l) {
    __builtin_amdgcn_global_load_lds(
        (__attribute__((address_space(1))) void*)g,
        (__attribute__((address_space(3))) void*)l,
        16, 0, 0);
}

template<int N>
__device__ __forceinline__ float dppror(float v) {
    return __int_as_float(__builtin_amdgcn_update_dpp(
        0, __float_as_int(v), 0x120 + N, 0xF, 0xF, false));
}

__device__ __forceinline__ void t2push(float& a1, float& a2, float v) {
    float hi = fmaxf(a1, v);
    float lo = fminf(a1, v);
    a1 = hi;
    a2 = fmaxf(a2, lo);
}

__device__ __forceinline__ void t2merge(float& a1, float& a2, float b1, float b2) {
    float hi = fmaxf(a1, b1);
    float lo = fminf(a1, b1);
    a1 = hi;
    a2 = fmaxf(fmaxf(a2, b2), lo);
}

// ---------------- Kernel A: row L2-normalize, fp32 -> bf16 ----------------
__global__ __launch_bounds__(256) void knorm(const float* __restrict__ x,
                                             unsigned short* __restrict__ xn) {
    const int w = threadIdx.x >> 6, lane = threadIdx.x & 63;
    const int row = blockIdx.x * 4 + w;
    const float4* src = (const float4*)(x + (size_t)row * DIM);
    float4 v[4];
    float ss = 0.0f;
    #pragma unroll
    for (int i = 0; i < 4; i++) {
        v[i] = src[lane + 64 * i];
        ss += v[i].x * v[i].x + v[i].y * v[i].y + v[i].z * v[i].z + v[i].w * v[i].w;
    }
    #pragma unroll
    for (int d = 1; d < 64; d <<= 1) ss += __shfl_xor(ss, d);
    const float inv = 1.0f / fmaxf(sqrtf(ss), 1e-8f);
    unsigned short* dst = xn + (size_t)row * DIM;
    #pragma unroll
    for (int i = 0; i < 4; i++) {
        uint2 o;
        o.x = (unsigned)f2bf(v[i].x * inv) | ((unsigned)f2bf(v[i].y * inv) << 16);
        o.y = (unsigned)f2bf(v[i].z * inv) | ((unsigned)f2bf(v[i].w * inv) << 16);
        *(uint2*)(dst + (size_t)(lane + 64 * i) * 4) = o;
    }
}

// ------- Kernel B: symmetric 256x256 gram, 8 waves, BK=64, 8-phase-style
// schedule: 4 phases/K-tile, 1 half-tile stage per phase, counted vmcnt(8),
// raw barriers (never drain vmcnt to 0 mid-loop). Fused top-2 epilogue.
//
// LDS map (131072 B): A region(buf b, khalf h) at b*32768 + h*16384;
//                     B region(b,h) at 65536 + b*32768 + h*16384.
// Region = 256 rows x 32 K bf16 (64 B/row), 16B-chunk j of row r stored at
// slot j ^ ((r>>1)&3)  [R5-verified: 0 bank conflicts].
// Epilogue scratch overlays smem[0..12288) after the K-loop (regions dead).
__global__ __launch_bounds__(512, 2) void kgram(const unsigned short* __restrict__ xn,
                                                float2* __restrict__ top2) {
    __shared__ __align__(16) char smem[131072];
    float (*st2r)[256][2] = (float (*)[256][2])(smem);          // [4][256][2]
    float (*st2c)[256][2] = (float (*)[256][2])(smem + 8192);   // [2][256][2]

    const int t = threadIdx.x;
    const int lane = t & 63;
    const int w = t >> 6;            // 0..7
    const int wr = w >> 2, wc = w & 3;
    const int g = lane >> 4, c = lane & 15;
    const int cswz = (c >> 1) & 3;

    // XCD-bijective swizzle: 528 = 8 * 66
    const int bid = (blockIdx.x & 7) * 66 + (blockIdx.x >> 3);
    int by = (int)((sqrtf(8.0f * (float)bid + 1.0f) - 1.0f) * 0.5f);
    while ((by + 1) * (by + 2) / 2 <= bid) by++;
    while (by * (by + 1) / 2 > bid) by--;
    const int bx = bid - by * (by + 1) / 2;
    const bool diagTile = (bx == by);

    // staging constants: thread covers stored chunks q0=t, q1=512+t of a region
    const int q0 = t, q1 = 512 + t;
    const int r0 = q0 >> 2, c0 = (q0 & 3) ^ ((r0 >> 1) & 3);
    const int r1 = q1 >> 2, c1 = (q1 & 3) ^ ((r1 >> 1) & 3);
    const unsigned short* gA0p = xn + (size_t)(by * BT + r0) * DIM + c0 * 8;
    const unsigned short* gA1p = xn + (size_t)(by * BT + r1) * DIM + c1 * 8;
    const unsigned short* gB0p = xn + (size_t)(bx * BT + r0) * DIM + c0 * 8;
    const unsigned short* gB1p = xn + (size_t)(bx * BT + r1) * DIM + c1 * 8;

    // read-side fragment byte offsets (add MH*4096 / frag*1024 / region base)
    const int aOff = (wr * 128 + c) * 64 + ((g ^ cswz) & 3) * 16;
    const int bOff = 65536 + (wc * 64 + c) * 64 + ((g ^ cswz) & 3) * 16;

    f32x4 acc[8][4];
    #pragma unroll
    for (int m = 0; m < 8; m++)
        #pragma unroll
        for (int n = 0; n < 4; n++) acc[m][n] = (f32x4)0.0f;

    bf16x8 aX0, aX1, aX2, aX3, aY0, aY1, aY2, aY3;
    bf16x8 bA0, bA1, bA2, bA3, bB0, bB1, bB2, bB3;

#define STG_A(BUF, H, KT) do {                                   \
        char* _d = smem + (BUF) * 32768 + (H) * 16384 + t * 16;  \
        gld16(gA0p + (KT) * 64 + (H) * 32, _d);                  \
        gld16(gA1p + (KT) * 64 + (H) * 32, _d + 8192);           \
    } while (0)
#define STG_B(BUF, H, KT) do {                                           \
        char* _d = smem + 65536 + (BUF) * 32768 + (H) * 16384 + t * 16;  \
        gld16(gB0p + (KT) * 64 + (H) * 32, _d);                          \
        gld16(gB1p + (KT) * 64 + (H) * 32, _d + 8192);                   \
    } while (0)
#define LDA4(D0, D1, D2, D3, BUF, H, MH) do {                                 \
        const char* _p = smem + (BUF) * 32768 + (H) * 16384 + (MH) * 4096 + aOff; \
        D0 = *(const bf16x8*)(_p);                                            \
        D1 = *(const bf16x8*)(_p + 1024);                                     \
        D2 = *(const bf16x8*)(_p + 2048);                                     \
        D3 = *(const bf16x8*)(_p + 3072);                                     \
    } while (0)
#define LDB4(D0, D1, D2, D3, BUF, H) do {                        \
        const char* _p = smem + (BUF) * 32768 + (H) * 16384 + bOff; \
        D0 = *(const bf16x8*)(_p);                               \
        D1 = *(const bf16x8*)(_p + 1024);                        \
        D2 = *(const bf16x8*)(_p + 2048);                        \
        D3 = *(const bf16x8*)(_p + 3072);                        \
    } while (0)
#define MF(a, b, cc) __builtin_amdgcn_mfma_f32_16x16x32_bf16(a, b, cc, 0, 0, 0)
#define MQUAD(MB, A0_, A1_, A2_, A3_, B0_, B1_, B2_, B3_) do {              \
        acc[(MB)+0][0]=MF(A0_,B0_,acc[(MB)+0][0]); acc[(MB)+0][1]=MF(A0_,B1_,acc[(MB)+0][1]); \
        acc[(MB)+0][2]=MF(A0_,B2_,acc[(MB)+0][2]); acc[(MB)+0][3]=MF(A0_,B3_,acc[(MB)+0][3]); \
        acc[(MB)+1][0]=MF(A1_,B0_,acc[(MB)+1][0]); acc[(MB)+1][1]=MF(A1_,B1_,acc[(MB)+1][1]); \
        acc[(MB)+1][2]=MF(A1_,B2_,acc[(MB)+1][2]); acc[(MB)+1][3]=MF(A1_,B3_,acc[(MB)+1][3]); \
        acc[(MB)+2][0]=MF(A2_,B0_,acc[(MB)+2][0]); acc[(MB)+2][1]=MF(A2_,B1_,acc[(MB)+2][1]); \
        acc[(MB)+2][2]=MF(A2_,B2_,acc[(MB)+2][2]); acc[(MB)+2][3]=MF(A2_,B3_,acc[(MB)+2][3]); \
        acc[(MB)+3][0]=MF(A3_,B0_,acc[(MB)+3][0]); acc[(MB)+3][1]=MF(A3_,B1_,acc[(MB)+3][1]); \
        acc[(MB)+3][2]=MF(A3_,B2_,acc[(MB)+3][2]); acc[(MB)+3][3]=MF(A3_,B3_,acc[(MB)+3][3]); \
    } while (0)
#define BAR1_LGKM                                          \
        __builtin_amdgcn_sched_barrier(0);                 \
        __builtin_amdgcn_s_barrier();                      \
        asm volatile("s_waitcnt lgkmcnt(0)" ::: "memory"); \
        __builtin_amdgcn_sched_barrier(0)
#define ENDPH                                              \
        __builtin_amdgcn_sched_barrier(0);                 \
        __builtin_amdgcn_s_barrier()
#define ENDPH_VM(N)                                        \
        __builtin_amdgcn_sched_barrier(0);                 \
        asm volatile("s_waitcnt vmcnt(" #N ")" ::: "memory"); \
        __builtin_amdgcn_s_barrier()

// One K-tile = 4 phases. Stages: P1:A-k1(J+1), P2:B-k1(J+1), P3:A-k0(J+2),
// P4:B-k0(J+2). vmcnt placed BEFORE the closing barrier so the barrier makes
// the per-wave count block-wide.
#define KTILE(J, BUF, S12, S34, VMA, VMB) do {                         \
        /* P1: k0, m0-3 */                                             \
        LDA4(aX0, aX1, aX2, aX3, BUF, 0, 0);                           \
        LDB4(bA0, bA1, bA2, bA3, BUF, 0);                              \
        if (S12) STG_A((BUF) ^ 1, 1, (J) + 1);                         \
        BAR1_LGKM;                                                     \
        __builtin_amdgcn_s_setprio(1);                                 \
        MQUAD(0, aX0, aX1, aX2, aX3, bA0, bA1, bA2, bA3);              \
        __builtin_amdgcn_s_setprio(0);                                 \
        ENDPH;                                                         \
        /* P2: k0, m4-7 */                                             \
        LDA4(aY0, aY1, aY2, aY3, BUF, 0, 1);                           \
        if (S12) STG_B((BUF) ^ 1, 1, (J) + 1);                         \
        BAR1_LGKM;                                                     \
        __builtin_amdgcn_s_setprio(1);                                 \
        MQUAD(4, aY0, aY1, aY2, aY3, bA0, bA1, bA2, bA3);              \
        __builtin_amdgcn_s_setprio(0);                                 \
        ENDPH_VM(VMA);                                                 \
        /* P3: k1, m0-3 */                                             \
        LDA4(aX0, aX1, aX2, aX3, BUF, 1, 0);                           \
        LDB4(bB0, bB1, bB2, bB3, BUF, 1);                              \
        if (S34) STG_A(BUF, 0, (J) + 2);                               \
        BAR1_LGKM;                                                     \
        __builtin_amdgcn_s_setprio(1);                                 \
        MQUAD(0, aX0, aX1, aX2, aX3, bB0, bB1, bB2, bB3);              \
        __builtin_amdgcn_s_setprio(0);                                 \
        ENDPH;                                                         \
        /* P4: k1, m4-7 */                                             \
        LDA4(aY0, aY1, aY2, aY3, BUF, 1, 1);                           \
        if (S34) STG_B(BUF, 0, (J) + 2);                               \
        BAR1_LGKM;                                                     \
        __builtin_amdgcn_s_setprio(1);                                 \
        MQUAD(4, aY0, aY1, aY2, aY3, bB0, bB1, bB2, bB3);              \
        __builtin_amdgcn_s_setprio(0);                                 \
        ENDPH_VM(VMB);                                                 \
    } while (0)

    // prologue: steady-state stage order for virtual tiles -2,-1 (12 loads);
    // vmcnt(8) retires A-k0(0),B-k0(0); barrier makes it block-wide.
    STG_A(0, 0, 0); STG_B(0, 0, 0);
    STG_A(0, 1, 0); STG_B(0, 1, 0);
    STG_A(1, 0, 1); STG_B(1, 0, 1);
    __builtin_amdgcn_sched_barrier(0);
    asm volatile("s_waitcnt vmcnt(8)" ::: "memory");
    __builtin_amdgcn_s_barrier();
    __builtin_amdgcn_sched_barrier(0);

    #pragma unroll 1
    for (int jj = 0; jj < 7; ++jj) {
        const int j0 = jj * 2;
        KTILE(j0,     0, 1, 1, 8, 8);
        KTILE(j0 + 1, 1, 1, 1, 8, 8);
    }
    KTILE(14, 0, 1, 0, 8, 4);
    KTILE(15, 1, 0, 0, 0, 0);

#undef KTILE
#undef ENDPH_VM
#undef ENDPH
#undef BAR1_LGKM
#undef MQUAD
#undef MF
#undef LDB4
#undef LDA4
#undef STG_B
#undef STG_A

    // ---- per-row top-2 (rows of by-block); C frag: row=g*4+rr, col=c ----
    #pragma unroll
    for (int m = 0; m < 8; m++) {
        #pragma unroll
        for (int rr = 0; rr < 4; rr++) {
            const int lrow = wr * 128 + m * 16 + g * 4 + rr;
            float a1 = -1e30f, a2 = -1e30f;
            #pragma unroll
            for (int n = 0; n < 4; n++) {
                float v = acc[m][n][rr];
                if (diagTile && (wc * 64 + n * 16 + c) == lrow) v = -2.0f;
                t2push(a1, a2, v);
            }
            { float b1 = dppror<1>(a1), b2 = dppror<1>(a2); t2merge(a1, a2, b1, b2); }
            { float b1 = dppror<2>(a1), b2 = dppror<2>(a2); t2merge(a1, a2, b1, b2); }
            { float b1 = dppror<4>(a1), b2 = dppror<4>(a2); t2merge(a1, a2, b1, b2); }
            { float b1 = dppror<8>(a1), b2 = dppror<8>(a2); t2merge(a1, a2, b1, b2); }
            if (c == 0) { st2r[wc][lrow][0] = a1; st2r[wc][lrow][1] = a2; }
        }
    }
    // ---- per-col top-2 (rows of bx-block via symmetry) ----
    if (!diagTile) {
        #pragma unroll
        for (int n = 0; n < 4; n++) {
            const int lcol = wc * 64 + n * 16 + c;
            float a1 = -1e30f, a2 = -1e30f;
            #pragma unroll
            for (int m = 0; m < 8; m++)
                #pragma unroll
                for (int rr = 0; rr < 4; rr++)
                    t2push(a1, a2, acc[m][n][rr]);
            #pragma unroll
            for (int d = 16; d < 64; d <<= 1) {
                float b1 = __shfl_xor(a1, d);
                float b2 = __shfl_xor(a2, d);
                t2merge(a1, a2, b1, b2);
            }
            if (g == 0) { st2c[wr][lcol][0] = a1; st2c[wr][lcol][1] = a2; }
        }
    }
    __syncthreads();
    if (t < 256) {
        float a1 = st2r[0][t][0], a2 = st2r[0][t][1];
        t2merge(a1, a2, st2r[1][t][0], st2r[1][t][1]);
        t2merge(a1, a2, st2r[2][t][0], st2r[2][t][1]);
        t2merge(a1, a2, st2r[3][t][0], st2r[3][t][1]);
        top2[(size_t)(by * BT + t) * NCHUNK + bx] = make_float2(a1, a2);
    } else if (!diagTile) {
        const int tc = t - 256;
        float a1 = st2c[0][tc][0], a2 = st2c[0][tc][1];
        t2merge(a1, a2, st2c[1][tc][0], st2c[1][tc][1]);
        top2[(size_t)(bx * BT + tc) * NCHUNK + by] = make_float2(a1, a2);
    }
}

// ------- Kernel C: one wave per row; lanes 0..31 <-> chunks; loss/gate -------
__global__ __launch_bounds__(256) void kloss(const float2* __restrict__ top2,
                                             float2* __restrict__ partials) {
    const int t = threadIdx.x;
    const int w = t >> 6, lane = t & 63;
    const int row = blockIdx.x * 4 + w;   // 2048 blocks x 4 waves
    float a1 = -1e30f, a2 = -1e30f;
    if (lane < NCHUNK) {
        float2 q = top2[(size_t)row * NCHUNK + lane];
        a1 = q.x; a2 = q.y;
    }
    #pragma unroll
    for (int d = 1; d < 64; d <<= 1) {
        float b1 = __shfl_xor(a1, d);
        float b2 = __shfl_xor(a2, d);
        t2merge(a1, a2, b1, b2);
    }
    __shared__ float2 wsum[4];
    if (lane == 0) {
        float slg = 0.0f, sg = 0.0f;
        float vs[2] = {a1, a2};
        #pragma unroll
        for (int i = 0; i < 2; i++) {
            float dd = sqrtf(fmaxf(2.0f - 2.0f * vs[i], 0.0f));
            float loss = -logf(dd + 1e-8f);
            float gate = 1.0f / (1.0f + expf(-(loss - 0.5f) * 10.0f));
            slg += loss * gate;
            sg += gate;
        }
        wsum[w] = make_float2(slg, sg);
    }
    __syncthreads();
    if (t == 0) {
        float a = 0.0f, b = 0.0f;
        #pragma unroll
        for (int i = 0; i < 4; i++) { a += wsum[i].x; b += wsum[i].y; }
        partials[blockIdx.x] = make_float2(a, b);
    }
}

// ---------------- Kernel D: final scalar over 2048 partials ----------------
__global__ __launch_bounds__(256) void kfinal(const float2* __restrict__ partials,
                                              float* __restrict__ out) {
    const int t = threadIdx.x;
    float a = 0.0f, b = 0.0f;
    for (int i = t; i < 2048; i += 256) {
        float2 p = partials[i];
        a += p.x; b += p.y;
    }
    #pragma unroll
    for (int d = 1; d < 64; d <<= 1) {
        a += __shfl_xor(a, d);
        b += __shfl_xor(b, d);
    }
    __shared__ float2 ws4[4];
    if ((t & 63) == 0) ws4[t >> 6] = make_float2(a, b);
    __syncthreads();
    if (t == 0) {
        float A = 0.0f, Bb = 0.0f;
        #pragma unroll
        for (int i = 0; i < 4; i++) { A += ws4[i].x; Bb += ws4[i].y; }
        float wm = A / 16384.0f;
        float gm = A / fmaxf(Bb, 1.0f);
        out[0] = 0.5f * wm + 0.5f * gm;
    }
}

extern "C" void kernel_launch(void* const* d_in, const int* in_sizes, int n_in,
                              void* d_out, int out_size, void* d_ws, size_t ws_size,
                              hipStream_t stream) {
    const float* x = (const float*)d_in[0];
    unsigned short* xn = (unsigned short*)d_ws;                              // 16 MB
    float2* top2 = (float2*)((char*)d_ws + (size_t)16 * 1024 * 1024);        // 2 MB
    float2* partials = (float2*)((char*)d_ws + (size_t)20 * 1024 * 1024);    // 16 KB
    float* out = (float*)d_out;

    knorm<<<NROWS / 4, 256, 0, stream>>>(x, xn);
    kgram<<<NTRI, 512, 0, stream>>>(xn, top2);
    kloss<<<2048, 256, 0, stream>>>(top2, partials);
    kfinal<<<1, 256, 0, stream>>>(partials, out);
}